// Round 1
// baseline (1290.238 us; speedup 1.0000x reference)
//
#include <hip/hip_runtime.h>
#include <math.h>

#define B_    8
#define N_    1024
#define FIN   512
#define FOUT  256
#define H_    8
#define ALPHA 0.2f
#define NEGV  -1e9f

// ---------------------------------------------------------------------------
// Kernel 1: projection GEMM  h_all[hb][n][o] = sum_f x[b][n][f] * W[h][o][f]
// 64x64 tile, BK=16, 256 threads, 4x4 register tile per thread. fp32.
// ---------------------------------------------------------------------------
#define BM 64
#define BN 64
#define BK 16

__global__ __launch_bounds__(256) void proj_gemm(
    const float* __restrict__ x, const float* __restrict__ W,
    float* __restrict__ h_all) {
  __shared__ float As[BK][BM + 4];
  __shared__ float Bs[BK][BN + 4];
  const int hb = blockIdx.z;
  const int h = hb >> 3, b = hb & 7;
  const float* A  = x + (size_t)b * N_ * FIN;      // (N, FIN) row-major
  const float* Bw = W + (size_t)h * FOUT * FIN;    // (FOUT, FIN) row-major
  float* C = h_all + (size_t)hb * N_ * FOUT;

  const int m0 = blockIdx.x * BM;
  const int n0 = blockIdx.y * BN;
  const int tid = threadIdx.x;
  const int tx = tid & 15, ty = tid >> 4;
  const int lr = tid >> 2, lc = (tid & 3) << 2;    // loader: row 0..63, col {0,4,8,12}

  float acc[4][4] = {{0.f}};

  for (int k0 = 0; k0 < FIN; k0 += BK) {
    float4 av = *(const float4*)(A  + (size_t)(m0 + lr) * FIN + k0 + lc);
    float4 bv = *(const float4*)(Bw + (size_t)(n0 + lr) * FIN + k0 + lc);
    As[lc + 0][lr] = av.x; As[lc + 1][lr] = av.y;
    As[lc + 2][lr] = av.z; As[lc + 3][lr] = av.w;
    Bs[lc + 0][lr] = bv.x; Bs[lc + 1][lr] = bv.y;
    Bs[lc + 2][lr] = bv.z; Bs[lc + 3][lr] = bv.w;
    __syncthreads();
#pragma unroll
    for (int k = 0; k < BK; ++k) {
      float4 a  = *(const float4*)&As[k][ty << 2];
      float4 bb = *(const float4*)&Bs[k][tx << 2];
      float ar[4] = {a.x, a.y, a.z, a.w};
      float br[4] = {bb.x, bb.y, bb.z, bb.w};
#pragma unroll
      for (int i = 0; i < 4; ++i)
#pragma unroll
        for (int j = 0; j < 4; ++j) acc[i][j] += ar[i] * br[j];
    }
    __syncthreads();
  }
#pragma unroll
  for (int i = 0; i < 4; ++i) {
    float4 v = make_float4(acc[i][0], acc[i][1], acc[i][2], acc[i][3]);
    *(float4*)(C + (size_t)(m0 + (ty << 2) + i) * FOUT + n0 + (tx << 2)) = v;
  }
}

// ---------------------------------------------------------------------------
// Kernel 2: f1[hb][n] = h_all[hb][n][:] . a1[h],  f2 likewise. Wave per row.
// ---------------------------------------------------------------------------
__global__ __launch_bounds__(256) void attn_coef(
    const float* __restrict__ h_all, const float* __restrict__ a1,
    const float* __restrict__ a2, float* __restrict__ f1,
    float* __restrict__ f2) {
  const int gw = (blockIdx.x * 256 + threadIdx.x) >> 6;  // row = hb*N + n
  const int lane = threadIdx.x & 63;
  const int h = gw >> 13;                                // / (B_*N_)
  const float* hr = h_all + (size_t)gw * FOUT;
  const float* A1 = a1 + h * FOUT;
  const float* A2 = a2 + h * FOUT;
  float s1 = 0.f, s2 = 0.f;
#pragma unroll
  for (int c = 0; c < FOUT / 64; ++c) {
    float hv = hr[lane + 64 * c];
    s1 += hv * A1[lane + 64 * c];
    s2 += hv * A2[lane + 64 * c];
  }
#pragma unroll
  for (int off = 32; off; off >>= 1) {
    s1 += __shfl_down(s1, off);
    s2 += __shfl_down(s2, off);
  }
  if (lane == 0) { f1[gw] = s1; f2[gw] = s2; }
}

// ---------------------------------------------------------------------------
// Kernel 3: fused attention + head-sum(elu) + log_softmax.
// Block = (b, 8-row i-tile), 256 threads (thread t owns output column o=t).
// Per head: each wave computes masked-LeakyReLU scores for 2 rows, softmax
// numerators into LDS (w), then all threads do PV accumulation.
// ---------------------------------------------------------------------------
#define TI 8

__global__ __launch_bounds__(256) void attn_apply(
    const float* __restrict__ h_all, const float* __restrict__ f1,
    const float* __restrict__ f2, const int* __restrict__ adj,
    float* __restrict__ out) {
  __shared__ float w[TI][N_];     // 32 KB: exp(e - m) per row
  __shared__ float s_rl[TI];      // row softmax denominators
  __shared__ float sc[4];         // cross-wave reduce scratch
  const int b = blockIdx.y;
  const int i0 = blockIdx.x * TI;
  const int tid = threadIdx.x;
  const int wid = tid >> 6, lane = tid & 63;

  float hsum[TI];
#pragma unroll
  for (int i = 0; i < TI; ++i) hsum[i] = 0.f;

  for (int h = 0; h < H_; ++h) {
    const int hb = h * B_ + b;
    const float* f2r = f2 + (size_t)hb * N_;
    // --- score pass: wave `wid` handles rows 2*wid, 2*wid+1 ---
#pragma unroll
    for (int rr = 0; rr < 2; ++rr) {
      const int i = wid * 2 + rr;
      const float f1i = f1[(size_t)hb * N_ + i0 + i];
      const int* adjr = adj + ((size_t)b * N_ + i0 + i) * N_;
      float ev[N_ / 64];
      float m = -3e38f;
#pragma unroll
      for (int c = 0; c < N_ / 64; ++c) {
        const int j = lane + 64 * c;
        float e = f1i + f2r[j];
        e = e > 0.f ? e : ALPHA * e;
        e = (adjr[j] == 0) ? NEGV : e;
        ev[c] = e;
        m = fmaxf(m, e);
      }
#pragma unroll
      for (int off = 32; off; off >>= 1) m = fmaxf(m, __shfl_xor(m, off));
      float l = 0.f;
#pragma unroll
      for (int c = 0; c < N_ / 64; ++c) {
        float ex = __expf(ev[c] - m);
        w[i][lane + 64 * c] = ex;
        l += ex;
      }
#pragma unroll
      for (int off = 32; off; off >>= 1) l += __shfl_xor(l, off);
      if (lane == 0) s_rl[i] = l;
    }
    __syncthreads();

    // --- PV: thread t accumulates out[i][o=t] = sum_j w[i][j]*h[hb][j][t] ---
    const float* hp = h_all + (size_t)hb * N_ * FOUT + tid;
    float acc[TI];
#pragma unroll
    for (int i = 0; i < TI; ++i) acc[i] = 0.f;
    for (int j = 0; j < N_; j += 4) {
      const float hv0 = hp[(size_t)(j + 0) * FOUT];
      const float hv1 = hp[(size_t)(j + 1) * FOUT];
      const float hv2 = hp[(size_t)(j + 2) * FOUT];
      const float hv3 = hp[(size_t)(j + 3) * FOUT];
#pragma unroll
      for (int i = 0; i < TI; ++i) {
        float4 wv = *(const float4*)&w[i][j];
        acc[i] += wv.x * hv0 + wv.y * hv1 + wv.z * hv2 + wv.w * hv3;
      }
    }
#pragma unroll
    for (int i = 0; i < TI; ++i) {
      const float oh = acc[i] / s_rl[i];
      hsum[i] += (oh > 0.f) ? oh : (__expf(oh) - 1.f);
    }
    __syncthreads();  // protect w/s_rl before next head overwrites
  }

  // --- log_softmax over o (across the 256 threads) per row ---
#pragma unroll
  for (int i = 0; i < TI; ++i) {
    const float v = hsum[i];
    float m = v;
#pragma unroll
    for (int off = 32; off; off >>= 1) m = fmaxf(m, __shfl_xor(m, off));
    if (lane == 0) sc[wid] = m;
    __syncthreads();
    m = fmaxf(fmaxf(sc[0], sc[1]), fmaxf(sc[2], sc[3]));
    __syncthreads();
    const float ex = __expf(v - m);
    float s = ex;
#pragma unroll
    for (int off = 32; off; off >>= 1) s += __shfl_xor(s, off);
    if (lane == 0) sc[wid] = s;
    __syncthreads();
    s = sc[0] + sc[1] + sc[2] + sc[3];
    __syncthreads();
    out[((size_t)b * N_ + i0 + i) * FOUT + tid] = v - m - logf(s);
  }
}

// ---------------------------------------------------------------------------
extern "C" void kernel_launch(void* const* d_in, const int* in_sizes, int n_in,
                              void* d_out, int out_size, void* d_ws,
                              size_t ws_size, hipStream_t stream) {
  const float* x   = (const float*)d_in[0];
  const int*   adj = (const int*)d_in[1];
  const float* W   = (const float*)d_in[2];
  const float* a1  = (const float*)d_in[3];
  const float* a2  = (const float*)d_in[4];
  float* out = (float*)d_out;

  float* h_all = (float*)d_ws;                       // H*B*N*FOUT = 16M floats
  float* f1 = h_all + (size_t)H_ * B_ * N_ * FOUT;   // 64K floats
  float* f2 = f1 + (size_t)H_ * B_ * N_;             // 64K floats

  dim3 g1(N_ / BM, FOUT / BN, H_ * B_);
  proj_gemm<<<g1, 256, 0, stream>>>(x, W, h_all);

  attn_coef<<<(H_ * B_ * N_) / 4, 256, 0, stream>>>(h_all, a1, a2, f1, f2);

  dim3 g3(N_ / TI, B_);
  attn_apply<<<g3, 256, 0, stream>>>(h_all, f1, f2, adj, out);
}

// Round 2
// 428.189 us; speedup vs baseline: 3.0132x; 3.0132x over previous
//
#include <hip/hip_runtime.h>
#include <math.h>

#define B_    8
#define N_    1024
#define FIN   512
#define FOUT  256
#define H_    8
#define ALPHA 0.2f
#define NEGV  -1e9f

#define XT (B_ * N_ * FIN)     // 4194304 x elements
#define WT (H_ * FOUT * FIN)   // 1048576 W elements

typedef short s16x8 __attribute__((ext_vector_type(8)));
typedef float f32x4 __attribute__((ext_vector_type(4)));

__device__ __forceinline__ unsigned short f2bf(float f) {
  unsigned int u = __float_as_uint(f);
  u = (u + 0x7FFFu + ((u >> 16) & 1u)) >> 16;   // round-to-nearest-even
  return (unsigned short)u;
}

// ---------------------------------------------------------------------------
// Kernel 0: fp32 -> bf16 conversion of x and W.
// ---------------------------------------------------------------------------
__global__ __launch_bounds__(256) void convert_bf16(
    const float* __restrict__ x, const float* __restrict__ W,
    unsigned short* __restrict__ xb, unsigned short* __restrict__ Wb) {
  const int i = (blockIdx.x * 256 + threadIdx.x) * 4;
  const float* src;
  unsigned short* dst;
  int off;
  if (i < XT) { src = x; dst = xb; off = i; }
  else        { src = W; dst = Wb; off = i - XT; }
  float4 v = *(const float4*)(src + off);
  ushort4 s;
  s.x = f2bf(v.x); s.y = f2bf(v.y); s.z = f2bf(v.z); s.w = f2bf(v.w);
  *(ushort4*)(dst + off) = s;
}

// ---------------------------------------------------------------------------
// Kernel 1: projection via MFMA.  ht[hb][o][n] (bf16, transposed) and
// f1/f2[hb][n] = h[n][:].a1/a2 fused via shfl-reduce + atomicAdd (fp32).
// Block: 256 thr = 4 waves; wave w does rows [bx*64+w*16, +16), cols [by*64,+64).
// ---------------------------------------------------------------------------
__global__ __launch_bounds__(256) void proj_mfma(
    const unsigned short* __restrict__ xb, const unsigned short* __restrict__ Wb,
    const float* __restrict__ a1, const float* __restrict__ a2,
    unsigned short* __restrict__ ht, float* __restrict__ f1,
    float* __restrict__ f2) {
  const int hb = blockIdx.z, h = hb >> 3, b = hb & 7;
  const int w = threadIdx.x >> 6, lane = threadIdx.x & 63;
  const int col = lane & 15, quad = lane >> 4;
  const int m0 = blockIdx.x * 64 + w * 16;
  const int o0 = blockIdx.y * 64;

  // A[m][k]: m = lane&15, k = quad*8 + j  (x row-major, contiguous 16B)
  const unsigned short* ap = xb + (size_t)(b * N_ + m0 + col) * FIN + quad * 8;
  // B[k][n]: n = lane&15 (= o), k = quad*8 + j -> Wb[o][k] contiguous 16B
  const unsigned short* bp = Wb + (size_t)(h * FOUT + o0 + col) * FIN + quad * 8;

  f32x4 acc[4];
  const f32x4 z4 = {0.f, 0.f, 0.f, 0.f};
#pragma unroll
  for (int t = 0; t < 4; ++t) acc[t] = z4;

  for (int k0 = 0; k0 < FIN; k0 += 32) {
    s16x8 af = *(const s16x8*)(ap + k0);
#pragma unroll
    for (int t = 0; t < 4; ++t) {
      s16x8 bf = *(const s16x8*)(bp + (size_t)t * 16 * FIN + k0);
      acc[t] = __builtin_amdgcn_mfma_f32_16x16x32_bf16(af, bf, acc[t], 0, 0, 0);
    }
  }

  // D layout: col(o) = lane&15, row(n) = quad*4 + reg
  float pf1[4] = {0.f, 0.f, 0.f, 0.f}, pf2[4] = {0.f, 0.f, 0.f, 0.f};
#pragma unroll
  for (int t = 0; t < 4; ++t) {
    const int o = o0 + t * 16 + col;
    const float va1 = a1[h * FOUT + o], va2 = a2[h * FOUT + o];
    unsigned short* hp = ht + (size_t)(hb * FOUT + o) * N_ + m0 + quad * 4;
    ushort4 st;
    st.x = f2bf(acc[t][0]); st.y = f2bf(acc[t][1]);
    st.z = f2bf(acc[t][2]); st.w = f2bf(acc[t][3]);
    *(ushort4*)hp = st;   // 4 consecutive n, 8B store
#pragma unroll
    for (int r = 0; r < 4; ++r) {
      pf1[r] += acc[t][r] * va1;
      pf2[r] += acc[t][r] * va2;
    }
  }
  // reduce over the 16 cols (o) within each quad
#pragma unroll
  for (int off = 1; off <= 8; off <<= 1) {
#pragma unroll
    for (int r = 0; r < 4; ++r) {
      pf1[r] += __shfl_xor(pf1[r], off);
      pf2[r] += __shfl_xor(pf2[r], off);
    }
  }
  if (col == 0) {
#pragma unroll
    for (int r = 0; r < 4; ++r) {
      const int n = m0 + quad * 4 + r;
      atomicAdd(&f1[hb * N_ + n], pf1[r]);
      atomicAdd(&f2[hb * N_ + n], pf2[r]);
    }
  }
}

// ---------------------------------------------------------------------------
// Kernel 2: fused attention. Block = 512 thr (8 waves), 32 query rows.
// Per head: score pass (masked LeakyReLU + softmax numerators -> bf16 LDS),
// then PV via MFMA (wave w: o in [w*32, w*32+32), both 16-row groups).
// ELU head-sum in registers; block log_softmax epilogue.
// ---------------------------------------------------------------------------
__global__ __launch_bounds__(512) void attn_mfma(
    const unsigned short* __restrict__ ht, const float* __restrict__ f1,
    const float* __restrict__ f2, const int* __restrict__ adj,
    float* __restrict__ out) {
  __shared__ __align__(16) unsigned short wlds[32][1032];  // +8 pad: banks
  __shared__ unsigned int adjb[32][32];
  __shared__ float s_rl[32];
  __shared__ float red[32][8];

  const int id = blockIdx.x;
  const int b = id & 7;                 // XCD k holds one b -> 4MB ht set in L2
  const int i0 = (id >> 3) * 32;
  const int tid = threadIdx.x, w = tid >> 6, lane = tid & 63;
  const int col = lane & 15, quad = lane >> 4;

  // adjacency bitmask: 32 rows x 1024 bits, built once, reused for 8 heads
  for (int wi = tid; wi < 32 * 32; wi += 512) {
    const int row = wi >> 5, word = wi & 31;
    const int* ap = adj + (size_t)(b * N_ + i0 + row) * N_ + word * 32;
    unsigned int bits = 0;
#pragma unroll
    for (int k = 0; k < 32; k += 4) {
      int4 v = *(const int4*)(ap + k);
      bits |= (v.x ? 1u : 0u) << k;
      bits |= (v.y ? 1u : 0u) << (k + 1);
      bits |= (v.z ? 1u : 0u) << (k + 2);
      bits |= (v.w ? 1u : 0u) << (k + 3);
    }
    adjb[row][word] = bits;
  }
  __syncthreads();

  float hsum[2][2][4];
#pragma unroll
  for (int g = 0; g < 2; ++g)
#pragma unroll
    for (int t = 0; t < 2; ++t)
#pragma unroll
      for (int r = 0; r < 4; ++r) hsum[g][t][r] = 0.f;

  for (int h = 0; h < H_; ++h) {
    const int hb = h * B_ + b;
    const float* f2r = f2 + (size_t)hb * N_;
    const float* f1r = f1 + (size_t)hb * N_ + i0;

    // ---- scores: wave w owns rows 4w..4w+3 ----
#pragma unroll
    for (int rr = 0; rr < 4; ++rr) {
      const int i = w * 4 + rr;
      const float f1i = f1r[i];
      float ev[16];
      float m = -3.0e38f;
#pragma unroll
      for (int c = 0; c < 16; ++c) {
        const int j = c * 64 + lane;
        float e = f1i + f2r[j];
        e = fmaxf(e, ALPHA * e);                       // LeakyReLU
        const unsigned int bits = adjb[i][2 * c + (lane >> 5)];
        e = ((bits >> (j & 31)) & 1u) ? e : NEGV;
        ev[c] = e;
        m = fmaxf(m, e);
      }
#pragma unroll
      for (int off = 32; off; off >>= 1) m = fmaxf(m, __shfl_xor(m, off));
      float l = 0.f;
#pragma unroll
      for (int c = 0; c < 16; ++c) {
        const float ex = __expf(ev[c] - m);
        l += ex;
        wlds[i][c * 64 + lane] = f2bf(ex);
      }
#pragma unroll
      for (int off = 32; off; off >>= 1) l += __shfl_xor(l, off);
      if (lane == 0) s_rl[i] = l;
    }
    __syncthreads();

    // ---- PV: D[i][o] = sum_j w[i][j] * h[j][o] ----
    f32x4 acc[2][2];
    const f32x4 z4 = {0.f, 0.f, 0.f, 0.f};
#pragma unroll
    for (int g = 0; g < 2; ++g)
#pragma unroll
      for (int t = 0; t < 2; ++t) acc[g][t] = z4;

    const unsigned short* bp = ht + (size_t)(hb * FOUT + w * 32 + col) * N_ + quad * 8;
    const unsigned short* a0p = &wlds[col][quad * 8];
    const unsigned short* a1p = &wlds[16 + col][quad * 8];
    for (int kk = 0; kk < 32; ++kk) {
      const int ko = kk * 32;
      s16x8 af0 = *(const s16x8*)(a0p + ko);
      s16x8 af1 = *(const s16x8*)(a1p + ko);
#pragma unroll
      for (int t = 0; t < 2; ++t) {
        s16x8 bf = *(const s16x8*)(bp + (size_t)t * 16 * N_ + ko);
        acc[0][t] = __builtin_amdgcn_mfma_f32_16x16x32_bf16(af0, bf, acc[0][t], 0, 0, 0);
        acc[1][t] = __builtin_amdgcn_mfma_f32_16x16x32_bf16(af1, bf, acc[1][t], 0, 0, 0);
      }
    }

    // divide by softmax denom, ELU, head-sum
#pragma unroll
    for (int g = 0; g < 2; ++g)
#pragma unroll
      for (int t = 0; t < 2; ++t)
#pragma unroll
        for (int r = 0; r < 4; ++r) {
          const float oh = acc[g][t][r] / s_rl[g * 16 + quad * 4 + r];
          hsum[g][t][r] += oh > 0.f ? oh : __expf(oh) - 1.f;
        }
    __syncthreads();   // wlds/s_rl reused next head
  }

  // ---- log_softmax over o (256) per row ----
  float mrow[2][4];
#pragma unroll
  for (int g = 0; g < 2; ++g)
#pragma unroll
    for (int r = 0; r < 4; ++r) {
      float mx = fmaxf(hsum[g][0][r], hsum[g][1][r]);
#pragma unroll
      for (int off = 1; off <= 8; off <<= 1) mx = fmaxf(mx, __shfl_xor(mx, off));
      if (col == 0) red[g * 16 + quad * 4 + r][w] = mx;
    }
  __syncthreads();
#pragma unroll
  for (int g = 0; g < 2; ++g)
#pragma unroll
    for (int r = 0; r < 4; ++r) {
      const int row = g * 16 + quad * 4 + r;
      float mx = red[row][0];
#pragma unroll
      for (int k = 1; k < 8; ++k) mx = fmaxf(mx, red[row][k]);
      mrow[g][r] = mx;
    }
  __syncthreads();
#pragma unroll
  for (int g = 0; g < 2; ++g)
#pragma unroll
    for (int r = 0; r < 4; ++r) {
      float s = __expf(hsum[g][0][r] - mrow[g][r]) +
                __expf(hsum[g][1][r] - mrow[g][r]);
#pragma unroll
      for (int off = 1; off <= 8; off <<= 1) s += __shfl_xor(s, off);
      if (col == 0) red[g * 16 + quad * 4 + r][w] = s;
    }
  __syncthreads();
#pragma unroll
  for (int g = 0; g < 2; ++g)
#pragma unroll
    for (int r = 0; r < 4; ++r) {
      const int row = g * 16 + quad * 4 + r;
      float s = 0.f;
#pragma unroll
      for (int k = 0; k < 8; ++k) s += red[row][k];
      const float lg = mrow[g][r] + logf(s);
#pragma unroll
      for (int t = 0; t < 2; ++t)
        out[(size_t)(b * N_ + i0 + row) * FOUT + w * 32 + t * 16 + col] =
            hsum[g][t][r] - lg;
    }
}

// ---------------------------------------------------------------------------
extern "C" void kernel_launch(void* const* d_in, const int* in_sizes, int n_in,
                              void* d_out, int out_size, void* d_ws,
                              size_t ws_size, hipStream_t stream) {
  const float* x   = (const float*)d_in[0];
  const int*   adj = (const int*)d_in[1];
  const float* W   = (const float*)d_in[2];
  const float* a1  = (const float*)d_in[3];
  const float* a2  = (const float*)d_in[4];
  float* out = (float*)d_out;

  unsigned short* ht = (unsigned short*)d_ws;             // 32 MB transposed h
  unsigned short* xb = ht + (size_t)H_ * B_ * FOUT * N_;  // 8 MB
  unsigned short* Wb = xb + (size_t)XT;                   // 2 MB
  float* f1 = (float*)(Wb + (size_t)WT);                  // 256 KB
  float* f2 = f1 + (size_t)H_ * B_ * N_;                  // 256 KB

  hipMemsetAsync(f1, 0, (size_t)2 * H_ * B_ * N_ * sizeof(float), stream);

  convert_bf16<<<(XT + WT) / 1024, 256, 0, stream>>>(x, W, xb, Wb);

  dim3 g1(N_ / 64, FOUT / 64, H_ * B_);
  proj_mfma<<<g1, 256, 0, stream>>>(xb, Wb, a1, a2, ht, f1, f2);

  attn_mfma<<<(N_ / 32) * B_, 512, 0, stream>>>(ht, f1, f2, adj, out);
}

// Round 3
// 268.208 us; speedup vs baseline: 4.8106x; 1.5965x over previous
//
#include <hip/hip_runtime.h>
#include <math.h>

#define B_    8
#define N_    1024
#define FIN   512
#define FOUT  256
#define H_    8
#define ALPHA 0.2f
#define NEGV  -1e9f

#define XT (B_ * N_ * FIN)     // 4194304 x elements
#define WT (H_ * FOUT * FIN)   // 1048576 W elements

typedef short s16x8 __attribute__((ext_vector_type(8)));
typedef float f32x4 __attribute__((ext_vector_type(4)));

__device__ __forceinline__ unsigned short f2bf(float f) {
  unsigned int u = __float_as_uint(f);
  u = (u + 0x7FFFu + ((u >> 16) & 1u)) >> 16;   // round-to-nearest-even
  return (unsigned short)u;
}

// ---------------------------------------------------------------------------
// Kernel 0: fp32 -> bf16 conversion of x and W.
// ---------------------------------------------------------------------------
__global__ __launch_bounds__(256) void convert_bf16(
    const float* __restrict__ x, const float* __restrict__ W,
    unsigned short* __restrict__ xb, unsigned short* __restrict__ Wb) {
  const int i = (blockIdx.x * 256 + threadIdx.x) * 4;
  const float* src;
  unsigned short* dst;
  int off;
  if (i < XT) { src = x; dst = xb; off = i; }
  else        { src = W; dst = Wb; off = i - XT; }
  float4 v = *(const float4*)(src + off);
  ushort4 s;
  s.x = f2bf(v.x); s.y = f2bf(v.y); s.z = f2bf(v.z); s.w = f2bf(v.w);
  *(ushort4*)(dst + off) = s;
}

// ---------------------------------------------------------------------------
// Kernel 1: projection GEMM, LDS-staged MFMA with register prefetch.
// C-tile 128(m) x 64(o), BK=64, 256 thr (4 waves, each 32m x 64o).
// LDS tiles stored [row][k] with XOR-swizzled 16B segments (no pad needed,
// conflict-free reads, 16B-aligned stores). Also fuses f1/f2 = h.a1/a2.
// ---------------------------------------------------------------------------
__global__ __launch_bounds__(256) void proj_mfma(
    const unsigned short* __restrict__ xb, const unsigned short* __restrict__ Wb,
    const float* __restrict__ a1, const float* __restrict__ a2,
    unsigned short* __restrict__ ht, float* __restrict__ f1,
    float* __restrict__ f2) {
  __shared__ __align__(16) unsigned short As[128 * 64];  // 16 KB
  __shared__ __align__(16) unsigned short Bs[64 * 64];   //  8 KB
  const int hb = blockIdx.z, h = hb >> 3, b = hb & 7;
  const int m0 = blockIdx.x * 128, o0 = blockIdx.y * 64;
  const int t = threadIdx.x, w = t >> 6, lane = t & 63;
  const int col = lane & 15, quad = lane >> 4;

  // staging map: thread t loads seg (t&7)^(srow&7) of row srow (+32 per call)
  const int srow = t >> 3;
  const int sslot = t & 7;
  const int sseg = sslot ^ (srow & 7);
  const unsigned short* agp = xb + (size_t)(b * N_ + m0 + srow) * FIN + sseg * 8;
  const unsigned short* bgp = Wb + (size_t)(h * FOUT + o0 + srow) * FIN + sseg * 8;

  f32x4 acc[2][4];
  const f32x4 z4 = {0.f, 0.f, 0.f, 0.f};
#pragma unroll
  for (int mt = 0; mt < 2; ++mt)
#pragma unroll
    for (int ot = 0; ot < 4; ++ot) acc[mt][ot] = z4;

  s16x8 pa[4], pb[2];
#pragma unroll
  for (int i2 = 0; i2 < 4; ++i2) pa[i2] = *(const s16x8*)(agp + (size_t)i2 * 32 * FIN);
#pragma unroll
  for (int i2 = 0; i2 < 2; ++i2) pb[i2] = *(const s16x8*)(bgp + (size_t)i2 * 32 * FIN);

  for (int it = 0; it < FIN / 64; ++it) {
    __syncthreads();
#pragma unroll
    for (int i2 = 0; i2 < 4; ++i2)
      *(s16x8*)&As[(i2 * 32 + srow) * 64 + sslot * 8] = pa[i2];
#pragma unroll
    for (int i2 = 0; i2 < 2; ++i2)
      *(s16x8*)&Bs[(i2 * 32 + srow) * 64 + sslot * 8] = pb[i2];
    __syncthreads();
    if (it < FIN / 64 - 1) {
      const int k0 = (it + 1) * 64;
#pragma unroll
      for (int i2 = 0; i2 < 4; ++i2)
        pa[i2] = *(const s16x8*)(agp + (size_t)i2 * 32 * FIN + k0);
#pragma unroll
      for (int i2 = 0; i2 < 2; ++i2)
        pb[i2] = *(const s16x8*)(bgp + (size_t)i2 * 32 * FIN + k0);
    }
#pragma unroll
    for (int kb = 0; kb < 2; ++kb) {
      s16x8 af[2], bf[4];
#pragma unroll
      for (int mt = 0; mt < 2; ++mt) {
        const int row = w * 32 + mt * 16 + col;
        af[mt] = *(const s16x8*)&As[row * 64 + ((kb * 4 + quad) ^ (row & 7)) * 8];
      }
#pragma unroll
      for (int ot = 0; ot < 4; ++ot) {
        const int row = ot * 16 + col;
        bf[ot] = *(const s16x8*)&Bs[row * 64 + ((kb * 4 + quad) ^ (row & 7)) * 8];
      }
#pragma unroll
      for (int mt = 0; mt < 2; ++mt)
#pragma unroll
        for (int ot = 0; ot < 4; ++ot)
          acc[mt][ot] = __builtin_amdgcn_mfma_f32_16x16x32_bf16(af[mt], bf[ot],
                                                                acc[mt][ot], 0, 0, 0);
    }
  }

  // epilogue: transposed bf16 store + fused f1/f2 partials
  float pf1[2][4] = {{0.f}}, pf2[2][4] = {{0.f}};
#pragma unroll
  for (int mt = 0; mt < 2; ++mt) {
#pragma unroll
    for (int ot = 0; ot < 4; ++ot) {
      const int o = o0 + ot * 16 + col;
      const float va1 = a1[h * FOUT + o], va2 = a2[h * FOUT + o];
      const int m = m0 + w * 32 + mt * 16 + quad * 4;
      ushort4 st;
      st.x = f2bf(acc[mt][ot][0]); st.y = f2bf(acc[mt][ot][1]);
      st.z = f2bf(acc[mt][ot][2]); st.w = f2bf(acc[mt][ot][3]);
      *(ushort4*)(ht + (size_t)(hb * FOUT + o) * N_ + m) = st;
#pragma unroll
      for (int r = 0; r < 4; ++r) {
        pf1[mt][r] += acc[mt][ot][r] * va1;
        pf2[mt][r] += acc[mt][ot][r] * va2;
      }
    }
  }
#pragma unroll
  for (int off = 1; off <= 8; off <<= 1)
#pragma unroll
    for (int mt = 0; mt < 2; ++mt)
#pragma unroll
      for (int r = 0; r < 4; ++r) {
        pf1[mt][r] += __shfl_xor(pf1[mt][r], off);
        pf2[mt][r] += __shfl_xor(pf2[mt][r], off);
      }
  if (col == 0) {
#pragma unroll
    for (int mt = 0; mt < 2; ++mt)
#pragma unroll
      for (int r = 0; r < 4; ++r) {
        const int n = m0 + w * 32 + mt * 16 + quad * 4 + r;
        atomicAdd(&f1[hb * N_ + n], pf1[mt][r]);
        atomicAdd(&f2[hb * N_ + n], pf2[mt][r]);
      }
  }
}

// ---------------------------------------------------------------------------
// Kernel 2: fused attention, head-group split (4 heads per block).
// Grid 512 = (b, group, i-tile): 2 resident blocks/CU -> phase overlap.
// Writes elu head-group partial sums (group 0 -> d_out, group 1 -> scratch).
// ---------------------------------------------------------------------------
__global__ __launch_bounds__(512) void attn_mfma(
    const unsigned short* __restrict__ ht, const float* __restrict__ f1,
    const float* __restrict__ f2, const int* __restrict__ adj,
    float* __restrict__ part0, float* __restrict__ part1) {
  __shared__ __align__(16) unsigned short wlds[32][1032];  // +8 pad
  __shared__ unsigned int adjb[32][32];
  __shared__ float s_rl[32];

  const int id = blockIdx.x;
  const int b = id & 7;                 // XCD round-robin keyed on b
  const int g0 = (id >> 3) & 1;        // head group: heads g0*4 .. g0*4+3
  const int i0 = (id >> 4) * 32;
  const int tid = threadIdx.x, w = tid >> 6, lane = tid & 63;
  const int col = lane & 15, quad = lane >> 4;

  // adjacency bitmask: 32 rows x 1024 bits, built once, reused for 4 heads
  for (int wi = tid; wi < 32 * 32; wi += 512) {
    const int row = wi >> 5, word = wi & 31;
    const int* ap = adj + (size_t)(b * N_ + i0 + row) * N_ + word * 32;
    unsigned int bits = 0;
#pragma unroll
    for (int k = 0; k < 32; k += 4) {
      int4 v = *(const int4*)(ap + k);
      bits |= (v.x ? 1u : 0u) << k;
      bits |= (v.y ? 1u : 0u) << (k + 1);
      bits |= (v.z ? 1u : 0u) << (k + 2);
      bits |= (v.w ? 1u : 0u) << (k + 3);
    }
    adjb[row][word] = bits;
  }
  __syncthreads();

  float hsum[2][2][4];
#pragma unroll
  for (int g = 0; g < 2; ++g)
#pragma unroll
    for (int t = 0; t < 2; ++t)
#pragma unroll
      for (int r = 0; r < 4; ++r) hsum[g][t][r] = 0.f;

  for (int hh = 0; hh < 4; ++hh) {
    const int h = g0 * 4 + hh;
    const int hb = h * B_ + b;
    const float* f2r = f2 + (size_t)hb * N_;
    const float* f1r = f1 + (size_t)hb * N_ + i0;

    // ---- scores: wave w owns rows 4w..4w+3 ----
#pragma unroll
    for (int rr = 0; rr < 4; ++rr) {
      const int i = w * 4 + rr;
      const float f1i = f1r[i];
      float ev[16];
      float m = -3.0e38f;
#pragma unroll
      for (int c = 0; c < 16; ++c) {
        const int j = c * 64 + lane;
        float e = f1i + f2r[j];
        e = fmaxf(e, ALPHA * e);                       // LeakyReLU
        const unsigned int bits = adjb[i][2 * c + (lane >> 5)];
        e = ((bits >> (j & 31)) & 1u) ? e : NEGV;
        ev[c] = e;
        m = fmaxf(m, e);
      }
#pragma unroll
      for (int off = 32; off; off >>= 1) m = fmaxf(m, __shfl_xor(m, off));
      float l = 0.f;
#pragma unroll
      for (int c = 0; c < 16; ++c) {
        const float ex = __expf(ev[c] - m);
        l += ex;
        wlds[i][c * 64 + lane] = f2bf(ex);
      }
#pragma unroll
      for (int off = 32; off; off >>= 1) l += __shfl_xor(l, off);
      if (lane == 0) s_rl[i] = l;
    }
    __syncthreads();

    // ---- PV: D[i][o] = sum_j w[i][j] * h[j][o], o-slice w*32..+32 ----
    f32x4 acc[2][2];
    const f32x4 z4 = {0.f, 0.f, 0.f, 0.f};
#pragma unroll
    for (int g = 0; g < 2; ++g)
#pragma unroll
      for (int t = 0; t < 2; ++t) acc[g][t] = z4;

    const unsigned short* bp = ht + (size_t)(hb * FOUT + w * 32 + col) * N_ + quad * 8;
    const unsigned short* a0p = &wlds[col][quad * 8];
    const unsigned short* a1p = &wlds[16 + col][quad * 8];
#pragma unroll 2
    for (int kk = 0; kk < 32; ++kk) {
      const int ko = kk * 32;
      s16x8 af0 = *(const s16x8*)(a0p + ko);
      s16x8 af1 = *(const s16x8*)(a1p + ko);
#pragma unroll
      for (int t = 0; t < 2; ++t) {
        s16x8 bf = *(const s16x8*)(bp + (size_t)t * 16 * N_ + ko);
        acc[0][t] = __builtin_amdgcn_mfma_f32_16x16x32_bf16(af0, bf, acc[0][t], 0, 0, 0);
        acc[1][t] = __builtin_amdgcn_mfma_f32_16x16x32_bf16(af1, bf, acc[1][t], 0, 0, 0);
      }
    }

    // divide by softmax denom, ELU, head-sum
#pragma unroll
    for (int g = 0; g < 2; ++g)
#pragma unroll
      for (int t = 0; t < 2; ++t)
#pragma unroll
        for (int r = 0; r < 4; ++r) {
          const float oh = acc[g][t][r] / s_rl[g * 16 + quad * 4 + r];
          hsum[g][t][r] += oh > 0.f ? oh : __expf(oh) - 1.f;
        }
    __syncthreads();   // wlds/s_rl reused next head
  }

  // ---- write head-group partial ----
  float* pdst = g0 ? part1 : part0;
#pragma unroll
  for (int g = 0; g < 2; ++g)
#pragma unroll
    for (int t = 0; t < 2; ++t)
#pragma unroll
      for (int r = 0; r < 4; ++r) {
        const int row = g * 16 + quad * 4 + r;
        pdst[(size_t)(b * N_ + i0 + row) * FOUT + w * 32 + t * 16 + col] =
            hsum[g][t][r];
      }
}

// ---------------------------------------------------------------------------
// Kernel 3: sum the 2 head-group partials + log_softmax over o.
// One wave per row (in-place on part0 == d_out is safe per-thread).
// ---------------------------------------------------------------------------
__global__ __launch_bounds__(256) void logsm(
    const float* __restrict__ part0, const float* __restrict__ part1,
    float* __restrict__ out) {
  const int row = blockIdx.x * 4 + (threadIdx.x >> 6);  // 0 .. B*N-1
  const int lane = threadIdx.x & 63;
  const float* p0 = part0 + (size_t)row * FOUT;
  const float* p1 = part1 + (size_t)row * FOUT;
  float v[4];
  float m = -3.0e38f;
#pragma unroll
  for (int c = 0; c < 4; ++c) {
    v[c] = p0[c * 64 + lane] + p1[c * 64 + lane];
    m = fmaxf(m, v[c]);
  }
#pragma unroll
  for (int off = 32; off; off >>= 1) m = fmaxf(m, __shfl_xor(m, off));
  float s = 0.f;
#pragma unroll
  for (int c = 0; c < 4; ++c) s += __expf(v[c] - m);
#pragma unroll
  for (int off = 32; off; off >>= 1) s += __shfl_xor(s, off);
  const float lg = m + logf(s);
#pragma unroll
  for (int c = 0; c < 4; ++c)
    out[(size_t)row * FOUT + c * 64 + lane] = v[c] - lg;
}

// ---------------------------------------------------------------------------
extern "C" void kernel_launch(void* const* d_in, const int* in_sizes, int n_in,
                              void* d_out, int out_size, void* d_ws,
                              size_t ws_size, hipStream_t stream) {
  const float* x   = (const float*)d_in[0];
  const int*   adj = (const int*)d_in[1];
  const float* W   = (const float*)d_in[2];
  const float* a1  = (const float*)d_in[3];
  const float* a2  = (const float*)d_in[4];
  float* out = (float*)d_out;

  unsigned short* ht = (unsigned short*)d_ws;             // 32 MB transposed h
  unsigned short* xb = ht + (size_t)H_ * B_ * FOUT * N_;  // 8 MB
  unsigned short* Wb = xb + (size_t)XT;                   // 2 MB
  float* f1 = (float*)(Wb + (size_t)WT);                  // 256 KB
  float* f2 = f1 + (size_t)H_ * B_ * N_;                  // 256 KB
  // head-group partials: group 0 -> d_out, group 1 -> xb region (dead after
  // proj_mfma; exactly B*N*FOUT floats = 8 MB). Stream-ordered reuse.
  float* part1 = (float*)xb;

  hipMemsetAsync(f1, 0, (size_t)2 * H_ * B_ * N_ * sizeof(float), stream);

  convert_bf16<<<(XT + WT) / 1024, 256, 0, stream>>>(x, W, xb, Wb);

  dim3 g1(N_ / 128, FOUT / 64, H_ * B_);
  proj_mfma<<<g1, 256, 0, stream>>>(xb, Wb, a1, a2, ht, f1, f2);

  attn_mfma<<<(N_ / 32) * B_ * 2, 512, 0, stream>>>(ht, f1, f2, adj, out, part1);

  logsm<<<(B_ * N_) / 4, 256, 0, stream>>>(out, part1, out);
}